// Round 7
// baseline (452.259 us; speedup 1.0000x reference)
//
#include <hip/hip_runtime.h>
#include <hip/hip_bf16.h>

typedef __bf16 bf16x8 __attribute__((ext_vector_type(8)));
typedef __bf16 bf16x2 __attribute__((ext_vector_type(2)));
typedef float f32x4 __attribute__((ext_vector_type(4)));

#define NROWS 100000
#define NSTRIPS 6250   // 100000 / 16, exact
#define EPS 1e-5f
#define SLOPE 0.2f
#define INVN 1e-5f     // 1.0f / 100000

__device__ __forceinline__ bf16x8 cvt8(const float* s) {
    float4 x0 = *(const float4*)s, x1 = *(const float4*)(s + 4);
    bf16x8 o;
    o[0] = (__bf16)x0.x; o[1] = (__bf16)x0.y; o[2] = (__bf16)x0.z; o[3] = (__bf16)x0.w;
    o[4] = (__bf16)x1.x; o[5] = (__bf16)x1.y; o[6] = (__bf16)x1.z; o[7] = (__bf16)x1.w;
    return o;
}

__device__ __forceinline__ bf16x8 cvt8v(float4 x0, float4 x1) {
    bf16x8 o;
    o[0] = (__bf16)x0.x; o[1] = (__bf16)x0.y; o[2] = (__bf16)x0.z; o[3] = (__bf16)x0.w;
    o[4] = (__bf16)x1.x; o[5] = (__bf16)x1.y; o[6] = (__bf16)x1.z; o[7] = (__bf16)x1.w;
    return o;
}

// ---- streaming GEMM: Y = LeakyReLU(A @ W^T + bias), + column sum/sumsq --------
// Round-7 diagnosis: r6 (W in LDS) was flat at 78us. Budget from counters:
// ~3.8k cycles per iteration-slot per CU vs ~400 cycles of issue -- waves stall
// ~3.4k cy per strip and the 64KB W-tile caps residency at 2 waves/SIMD, so
// the stall is unhideable. Fix is multiplicative:
//  (a) 32KB W-tiles (NC halved, y-split doubled; extra A re-reads are
//      L3-resident) -> bounds(256,4), 4 blocks/CU = 16 waves/CU;
//  (b) 2-deep A-prefetch (r1's ping-pong raw regs, static macro indexing) --
//      meaningful NOW because the A-chain is the only global dependency left
//      (r1's attempt was poisoned by the W-path).
// W-LDS layout (validated r6, conflicts ~0.3cy/read): element (c,k) at byte
// c*(KT*2) + ((k*2) ^ ((c&7)<<4)); both write and read are plain LDS accesses.
// A-frag: lane reads A[row0+l16][ks*32+quad*8 ..+8]. C/D: col=l16, row=quad*4+r.
template <int KT, int NI, int MINW, int NTOT, bool F32IN>
__global__ __launch_bounds__(256, MINW)
void gemm_wlds(const __bf16* __restrict__ A, const float* __restrict__ A32,
               const __bf16* __restrict__ W, const float* __restrict__ W32,
               const float* __restrict__ bias, __bf16* __restrict__ Y,
               float* __restrict__ sum, float* __restrict__ sumsq)
{
    constexpr int KS = KT / 32;
    constexpr int NC = 4 * NI * 16;        // cols per block (4 waves)
    constexpr int KC8 = KT / 8;            // 16B chunks per W row
    __shared__ __align__(16) char Wsh[NC * KT * 2];   // 32 KB

    const int tid = threadIdx.x;
    const int wave = tid >> 6, lane = tid & 63;
    const int quad = lane >> 4, l16 = lane & 15;
    const int cb = blockIdx.y * NC;        // block's first (global) column
    const int c0 = wave * (NI * 16);       // wave's first column (block-local)

    // ---- stage W slice -> LDS (bf16), coalesced global reads, swizzled writes
    for (int e = tid; e < NC * KC8; e += 256) {
        int c  = e / KC8;
        int kc = e % KC8;
        int gcol = cb + c;
        bf16x8 v;
        if constexpr (F32IN) v = cvt8(W32 + (size_t)gcol * KT + kc * 8);
        else                 v = *(const bf16x8*)(W + (size_t)gcol * KT + kc * 8);
        *(bf16x8*)(Wsh + c * (KT * 2) + ((kc * 16) ^ ((c & 7) << 4))) = v;
    }
    __syncthreads();

    float bcol[NI];
    #pragma unroll
    for (int ni = 0; ni < NI; ++ni) bcol[ni] = bias[cb + c0 + ni * 16 + l16];

    float csum[NI] = {}, csq[NI] = {};
    float4 rawf[2][KS][2];   // F32IN prefetch buffers (DCE'd otherwise)
    bf16x8 rawb[2][KS];      // bf16 prefetch buffers

#define LOAD_STRIP(BUF, S) do {                                                   \
        const int row_ = (S) * 16 + l16;                                          \
        _Pragma("unroll")                                                         \
        for (int ks = 0; ks < KS; ++ks) {                                         \
            const int k_ = ks * 32 + quad * 8;                                    \
            if constexpr (F32IN) {                                                \
                const float* p_ = A32 + (size_t)row_ * KT + k_;                   \
                rawf[BUF][ks][0] = *(const float4*)p_;                            \
                rawf[BUF][ks][1] = *(const float4*)(p_ + 4);                      \
            } else {                                                              \
                rawb[BUF][ks] = *(const bf16x8*)(A + (size_t)row_ * KT + k_);     \
            }                                                                     \
        }                                                                         \
    } while (0)

#define COMPUTE_STORE(BUF, S) do {                                                \
        bf16x8 af_[KS];                                                           \
        _Pragma("unroll")                                                         \
        for (int ks = 0; ks < KS; ++ks) {                                         \
            if constexpr (F32IN) af_[ks] = cvt8v(rawf[BUF][ks][0], rawf[BUF][ks][1]); \
            else                 af_[ks] = rawb[BUF][ks];                         \
        }                                                                         \
        f32x4 acc_[NI] = {};                                                      \
        _Pragma("unroll")                                                         \
        for (int ks = 0; ks < KS; ++ks) {                                         \
            const int kb_ = (ks * 32 + quad * 8) * 2;                             \
            _Pragma("unroll")                                                     \
            for (int ni = 0; ni < NI; ++ni) {                                     \
                const int c_ = c0 + ni * 16 + l16;                                \
                bf16x8 bf_ = *(const bf16x8*)(Wsh + c_ * (KT * 2) +               \
                                              (kb_ ^ ((c_ & 7) << 4)));           \
                acc_[ni] = __builtin_amdgcn_mfma_f32_16x16x32_bf16(               \
                    af_[ks], bf_, acc_[ni], 0, 0, 0);                             \
            }                                                                     \
        }                                                                         \
        const int row0_ = (S) * 16;                                               \
        _Pragma("unroll")                                                         \
        for (int ni = 0; ni < NI; ++ni) {                                         \
            int col_ = cb + c0 + ni * 16 + l16;                                   \
            _Pragma("unroll")                                                     \
            for (int r = 0; r < 4; ++r) {                                         \
                float y_ = acc_[ni][r] + bcol[ni];                                \
                y_ = (y_ > 0.f) ? y_ : SLOPE * y_;                                \
                Y[(size_t)(row0_ + quad * 4 + r) * NTOT + col_] = (__bf16)y_;     \
                csum[ni] += y_;                                                   \
                csq[ni]  += y_ * y_;                                              \
            }                                                                     \
        }                                                                         \
    } while (0)

    int g = blockIdx.x;
    const int stride = gridDim.x;
    if (g < NSTRIPS) {
        LOAD_STRIP(0, g);
        while (true) {
            int gn = g + stride;
            if (gn < NSTRIPS) LOAD_STRIP(1, gn);   // prefetch next strip
            COMPUTE_STORE(0, g);
            g = gn;
            if (g >= NSTRIPS) break;
            gn = g + stride;
            if (gn < NSTRIPS) LOAD_STRIP(0, gn);
            COMPUTE_STORE(1, g);
            g = gn;
            if (g >= NSTRIPS) break;
        }
    }
#undef LOAD_STRIP
#undef COMPUTE_STORE

    // column sums -> atomics (unchanged)
    #pragma unroll
    for (int ni = 0; ni < NI; ++ni) {
        float s = csum[ni], q = csq[ni];
        s += __shfl_xor(s, 16); s += __shfl_xor(s, 32);
        q += __shfl_xor(q, 16); q += __shfl_xor(q, 32);
        if (quad == 0) {
            int col = cb + c0 + ni * 16 + l16;
            atomicAdd(&sum[col], s);
            atomicAdd(&sumsq[col], q);
        }
    }
}

// ---- fused stats + fold: recompute s,t from column sums, fold BN into next W.
__global__ void fold_stats_k(const float* __restrict__ sum, const float* __restrict__ sumsq,
                             const float* __restrict__ g, const float* __restrict__ beta,
                             const float* __restrict__ W, const float* __restrict__ b,
                             __bf16* __restrict__ Wf, float* __restrict__ bf_, int K)
{
    __shared__ float s_sh[256], t_sh[256];
    const int n = blockIdx.x, lane = threadIdx.x;  // 64 threads = 1 wave
    for (int k = lane; k < K; k += 64) {
        float m = sum[k] * INVN;
        float v = sumsq[k] * INVN - m * m;
        float sc = g[k] * rsqrtf(v + EPS);
        s_sh[k] = sc;
        t_sh[k] = beta[k] - m * sc;
    }
    __syncthreads();
    float dot = 0.f;
    for (int k = lane; k < K; k += 64) {
        float w = W[(size_t)n * K + k];
        Wf[(size_t)n * K + k] = (__bf16)(w * s_sh[k]);
        dot += w * t_sh[k];
    }
    #pragma unroll
    for (int off = 32; off; off >>= 1) dot += __shfl_down(dot, off);
    if (lane == 0) bf_[n] = b[n] + dot;
}

// ---- fused finalize: stats3 inline + F output + neighbor-mean + BN-after-mean.
__global__ __launch_bounds__(256)
void finalize_k(const __bf16* __restrict__ Y3, const int* __restrict__ idx,
                const float* __restrict__ sum3, const float* __restrict__ sq3,
                const float* __restrict__ g3, const float* __restrict__ be3,
                float* __restrict__ F, float* __restrict__ out, int N)
{
    const int row = blockIdx.x * 4 + (threadIdx.x >> 6);  // one row per wave
    if (row >= N) return;
    const int lane = threadIdx.x & 63;
    const int c = lane * 2;

    const float2 sm = *(const float2*)(sum3 + c);
    const float2 sq = *(const float2*)(sq3 + c);
    const float2 gg = *(const float2*)(g3 + c);
    const float2 bb = *(const float2*)(be3 + c);
    const float m0 = sm.x * INVN, m1 = sm.y * INVN;
    const float v0 = sq.x * INVN - m0 * m0, v1 = sq.y * INVN - m1 * m1;
    const float s0 = gg.x * rsqrtf(v0 + EPS), s1 = gg.y * rsqrtf(v1 + EPS);
    const float t0 = bb.x - m0 * s0, t1 = bb.y - m1 * s1;

    bf16x2 own = *(const bf16x2*)(Y3 + (size_t)row * 128 + c);
    float2 f;
    f.x = (float)own[0] * s0 + t0;
    f.y = (float)own[1] * s1 + t1;
    *(float2*)(F + (size_t)row * 128 + c) = f;

    const int* ib = idx + (size_t)row * 16;
    float a0 = 0.f, a1 = 0.f;
    #pragma unroll
    for (int k = 0; k < 16; ++k) {
        const int j = ib[k];  // wave-uniform -> scalar load
        bf16x2 v = *(const bf16x2*)(Y3 + (size_t)j * 128 + c);
        a0 += (float)v[0];
        a1 += (float)v[1];
    }
    float2 o;
    o.x = a0 * 0.0625f * s0 + t0;
    o.y = a1 * 0.0625f * s1 + t1;
    *(float2*)(out + (size_t)row * 128 + c) = o;
}

extern "C" void kernel_launch(void* const* d_in, const int* in_sizes, int n_in,
                              void* d_out, int out_size, void* d_ws, size_t ws_size,
                              hipStream_t stream)
{
    const float* X   = (const float*)d_in[0];
    const int*   idx = (const int*)d_in[1];
    // d_in[2] = prob_retained (unused, ==1)
    const float* W1  = (const float*)d_in[3];
    const float* b1  = (const float*)d_in[4];
    const float* g1  = (const float*)d_in[5];
    const float* be1 = (const float*)d_in[6];
    const float* W2  = (const float*)d_in[7];
    const float* b2  = (const float*)d_in[8];
    const float* g2  = (const float*)d_in[9];
    const float* be2 = (const float*)d_in[10];
    const float* W3  = (const float*)d_in[11];
    const float* b3  = (const float*)d_in[12];
    const float* g3  = (const float*)d_in[13];
    const float* be3 = (const float*)d_in[14];

    char* ws = (char*)d_ws;
    float* sum1 = (float*)(ws + 0);
    float* sq1  = (float*)(ws + 1024);
    float* sum2 = (float*)(ws + 2048);
    float* sq2  = (float*)(ws + 3072);
    float* sum3 = (float*)(ws + 4096);
    float* sq3  = (float*)(ws + 4608);
    float* b2f  = (float*)(ws + 10240);
    float* b3f  = (float*)(ws + 11264);
    __bf16* W2f = (__bf16*)(ws + 13312);            // 256*256*2 = 131072 B
    __bf16* W3f = (__bf16*)(ws + 144384);           // 128*256*2 = 65536 B
    __bf16* Y1  = (__bf16*)(ws + (1 << 20));                   // [N,256] bf16 51.2 MB
    __bf16* Y2  = (__bf16*)(ws + (1 << 20) + 51200000);        // [N,256] bf16 51.2 MB
    __bf16* Y3  = Y1;  // [N,128]; Y1 dead after gemm2 (gemm3 reads only Y2)

    float* out_nu = (float*)d_out;                  // node_update [N,128] fp32
    float* F      = out_nu + (size_t)NROWS * 128;   // f [N,128] fp32

    hipMemsetAsync(d_ws, 0, 5120, stream);  // zero sum/sumsq accumulators

    // layer 1: X[100000,128] fp32 @ W1[256,128]^T
    // NC=128 (NI=2, y=2), W-LDS 32 KB, bounds(256,4) -> 4 blocks/CU = 16 waves/CU
    gemm_wlds<128, 2, 4, 256, true><<<dim3(512, 2), 256, 0, stream>>>(
        nullptr, X, nullptr, W1, b1, Y1, sum1, sq1);
    fold_stats_k<<<256, 64, 0, stream>>>(sum1, sq1, g1, be1, W2, b2, W2f, b2f, 256);

    // layer 2: Y1[100000,256] bf16 @ W2'[256,256]^T -> Y2
    // NC=64 (NI=1, y=4), W-LDS 32 KB, 4 blocks/CU = 16 waves/CU
    gemm_wlds<256, 1, 4, 256, false><<<dim3(256, 4), 256, 0, stream>>>(
        Y1, nullptr, W2f, nullptr, b2f, Y2, sum2, sq2);
    fold_stats_k<<<128, 64, 0, stream>>>(sum2, sq2, g2, be2, W3, b3, W3f, b3f, 256);

    // layer 3: Y2[100000,256] bf16 @ W3'[128,256]^T -> raw Y3 (pre-BN), NC=64 y=2
    gemm_wlds<256, 1, 4, 128, false><<<dim3(512, 2), 256, 0, stream>>>(
        Y2, nullptr, W3f, nullptr, b3f, Y3, sum3, sq3);

    // fused: stats3 + f-output + neighbor-mean
    finalize_k<<<25000, 256, 0, stream>>>(Y3, idx, sum3, sq3, g3, be3, F, out_nu, NROWS);
}

// Round 8
// 426.915 us; speedup vs baseline: 1.0594x; 1.0594x over previous
//
#include <hip/hip_runtime.h>
#include <hip/hip_bf16.h>

typedef __bf16 bf16x8 __attribute__((ext_vector_type(8)));
typedef __bf16 bf16x2 __attribute__((ext_vector_type(2)));
typedef float f32x4 __attribute__((ext_vector_type(4)));

#define NROWS 100000
#define NSTRIPS 6250   // 100000 / 16, exact
#define EPS 1e-5f
#define SLOPE 0.2f

__device__ __forceinline__ bf16x8 cvt8(const float* s) {
    float4 x0 = *(const float4*)s, x1 = *(const float4*)(s + 4);
    bf16x8 o;
    o[0] = (__bf16)x0.x; o[1] = (__bf16)x0.y; o[2] = (__bf16)x0.z; o[3] = (__bf16)x0.w;
    o[4] = (__bf16)x1.x; o[5] = (__bf16)x1.y; o[6] = (__bf16)x1.z; o[7] = (__bf16)x1.w;
    return o;
}

// ---- ROUND 8: measurement round ----------------------------------------------
// Pipeline = round-0 verbatim (best measured: 365.7us). Two probe kernels are
// appended AFTER the full pipeline; they read Y2 (valid bf16, dead after gemm3)
// and WRITE NOTHING (loads kept live via empty asm), so they cannot affect
// correctness under graph replay. They answer: is the MFMA-layout A-gather
// (16 rows x 512B stride per dwordx4) the hidden serializer?
//   probe<5>: exact real A-load pattern, 2x strip passes, 64KB dummy LDS to
//             replicate the 2-blocks/CU environment.
//   probe<6>: same bytes, same instr count, same environment, CONTIGUOUS.
// If scatter is guilty: probe<5> tops the dispatch table at ~2x gemm1 and
// probe<6> stays invisible. If both are fast, loads are innocent -> ablate
// stores next.

// ---- streaming GEMM: r0 verbatim ---------------------------------------------
template <int KT, int NI, bool F32IN>
__global__ __launch_bounds__(256, 2)
void gemm_stream(const __bf16* __restrict__ A, const float* __restrict__ A32,
                 const __bf16* __restrict__ W, const float* __restrict__ W32,
                 const float* __restrict__ bias, __bf16* __restrict__ Y,
                 float* __restrict__ sum, float* __restrict__ sumsq)
{
    constexpr int KS = KT / 32;
    constexpr int NCOLS = NI * 64;           // 4 waves * NI*16 columns
    const int wave = threadIdx.x >> 6, lane = threadIdx.x & 63;
    const int quad = lane >> 4, l16 = lane & 15;
    const int c0 = wave * (NI * 16);

    bf16x8 bfrag[NI][KS];
    float bcol[NI];
    #pragma unroll
    for (int ni = 0; ni < NI; ++ni) {
        int col = c0 + ni * 16 + l16;
        bcol[ni] = bias[col];
        #pragma unroll
        for (int ks = 0; ks < KS; ++ks) {
            int k = ks * 32 + quad * 8;
            if constexpr (F32IN) bfrag[ni][ks] = cvt8(W32 + (size_t)col * KT + k);
            else                 bfrag[ni][ks] = *(const bf16x8*)(W + (size_t)col * KT + k);
        }
    }

    float csum[NI] = {}, csq[NI] = {};

    for (int s = blockIdx.x; s < NSTRIPS; s += gridDim.x) {
        int row0 = s * 16;
        bf16x8 afrag[KS];
        #pragma unroll
        for (int ks = 0; ks < KS; ++ks) {
            int k = ks * 32 + quad * 8;
            if constexpr (F32IN) afrag[ks] = cvt8(A32 + (size_t)(row0 + l16) * KT + k);
            else                 afrag[ks] = *(const bf16x8*)(A + (size_t)(row0 + l16) * KT + k);
        }
        f32x4 acc[NI] = {};
        #pragma unroll
        for (int ks = 0; ks < KS; ++ks)
            #pragma unroll
            for (int ni = 0; ni < NI; ++ni)
                acc[ni] = __builtin_amdgcn_mfma_f32_16x16x32_bf16(
                    afrag[ks], bfrag[ni][ks], acc[ni], 0, 0, 0);

        #pragma unroll
        for (int ni = 0; ni < NI; ++ni) {
            int col = c0 + ni * 16 + l16;
            #pragma unroll
            for (int r = 0; r < 4; ++r) {
                float y = acc[ni][r] + bcol[ni];
                y = (y > 0.f) ? y : SLOPE * y;
                Y[(size_t)(row0 + quad * 4 + r) * NCOLS + col] = (__bf16)y;
                csum[ni] += y;
                csq[ni]  += y * y;
            }
        }
    }

    #pragma unroll
    for (int ni = 0; ni < NI; ++ni) {
        float s = csum[ni], q = csq[ni];
        s += __shfl_xor(s, 16); s += __shfl_xor(s, 32);
        q += __shfl_xor(q, 16); q += __shfl_xor(q, 32);
        if (quad == 0) {
            int col = c0 + ni * 16 + l16;
            atomicAdd(&sum[col], s);
            atomicAdd(&sumsq[col], q);
        }
    }
}

// ------------- stats: s = g*rsqrt(var+eps), t = beta - mean*s --------------------
__global__ void stats_k(const float* __restrict__ sum, const float* __restrict__ sumsq,
                        const float* __restrict__ g, const float* __restrict__ beta,
                        float* __restrict__ s, float* __restrict__ t,
                        int Ncols, float invN)
{
    int c = blockIdx.x * blockDim.x + threadIdx.x;
    if (c < Ncols) {
        float m = sum[c] * invN;
        float v = sumsq[c] * invN - m * m;
        float sc = g[c] * rsqrtf(v + EPS);
        s[c] = sc;
        t[c] = beta[c] - m * sc;
    }
}

// ------------- fold BN into next layer: W' = W*diag(s) (bf16), b' = b + W@t ------
__global__ void fold_k(const float* __restrict__ W, const float* __restrict__ b,
                       const float* __restrict__ s, const float* __restrict__ t,
                       __bf16* __restrict__ Wf, float* __restrict__ bf_, int K)
{
    int n = blockIdx.x;
    int lane = threadIdx.x;  // 64
    float dot = 0.f;
    for (int k = lane; k < K; k += 64) {
        float w = W[(size_t)n * K + k];
        Wf[(size_t)n * K + k] = (__bf16)(w * s[k]);
        dot += w * t[k];
    }
    #pragma unroll
    for (int off = 32; off; off >>= 1) dot += __shfl_down(dot, off);
    if (lane == 0) bf_[n] = b[n] + dot;
}

// ------------- final BN: F = Y3*s + t (fp32, straight into d_out) ----------------
__global__ void bn_apply(const __bf16* __restrict__ Y, const float* __restrict__ s,
                         const float* __restrict__ t, float* __restrict__ F, long n8)
{
    long i = blockIdx.x * (long)blockDim.x + threadIdx.x;
    if (i >= n8) return;
    bf16x8 v = *(const bf16x8*)(Y + i * 8);
    int c0 = (int)((i * 8) & 127);
    float4 f0, f1;
    f0.x = (float)v[0] * s[c0 + 0] + t[c0 + 0];
    f0.y = (float)v[1] * s[c0 + 1] + t[c0 + 1];
    f0.z = (float)v[2] * s[c0 + 2] + t[c0 + 2];
    f0.w = (float)v[3] * s[c0 + 3] + t[c0 + 3];
    f1.x = (float)v[4] * s[c0 + 4] + t[c0 + 4];
    f1.y = (float)v[5] * s[c0 + 5] + t[c0 + 5];
    f1.z = (float)v[6] * s[c0 + 6] + t[c0 + 6];
    f1.w = (float)v[7] * s[c0 + 7] + t[c0 + 7];
    *(float4*)(F + i * 8) = f0;
    *(float4*)(F + i * 8 + 4) = f1;
}

// ---- neighbor mean over bf16 pre-BN Y3, BN affine applied after the mean -------
__global__ __launch_bounds__(256)
void gather_mean_bn(const __bf16* __restrict__ Y3, const int* __restrict__ idx,
                    const float* __restrict__ s3, const float* __restrict__ t3,
                    float* __restrict__ out, int N)
{
    int row = blockIdx.x * 4 + (threadIdx.x >> 6);  // one row per wave
    if (row >= N) return;
    int lane = threadIdx.x & 63;
    const int* ib = idx + (size_t)row * 16;
    float a0 = 0.f, a1 = 0.f;
    #pragma unroll
    for (int k = 0; k < 16; ++k) {
        int j = ib[k];  // wave-uniform -> scalar load
        bf16x2 v = *(const bf16x2*)(Y3 + (size_t)j * 128 + lane * 2);
        a0 += (float)v[0];
        a1 += (float)v[1];
    }
    float2 sc = *(const float2*)(s3 + lane * 2);
    float2 tc = *(const float2*)(t3 + lane * 2);
    float2 o;
    o.x = a0 * 0.0625f * sc.x + tc.x;
    o.y = a1 * 0.0625f * sc.y + tc.y;
    *(float2*)(out + (size_t)row * 128 + lane * 2) = o;
}

// ---- DIAGNOSTIC PROBES (no stores, no side effects) ----------------------------
// V=5: exact real A-load gather: afrag[ks] <- A[(s*16+l16)*256 + ks*32+quad*8]
//      (16 rows x 512B stride per instruction, all 4 waves same addresses).
// V=6: identical bytes & instruction count, fully contiguous:
//      lane reads A[s*4096 + ks*512 + lane*8] (1KB contig per instruction).
// Both: 2 passes over all strips (amplification), 64KB dummy LDS pins
// occupancy to 2 blocks/CU (the real gemm2 environment).
template <int V>
__global__ __launch_bounds__(256, 2)
void probe_loads(const __bf16* __restrict__ A)
{
    __shared__ char dummy[65536];
    dummy[threadIdx.x] = (char)threadIdx.x;
    __syncthreads();

    const int lane = threadIdx.x & 63;
    const int quad = lane >> 4, l16 = lane & 15;

    for (int rep = 0; rep < 2; ++rep) {
        for (int s = blockIdx.x; s < NSTRIPS; s += gridDim.x) {
            bf16x8 afrag[8];
            #pragma unroll
            for (int ks = 0; ks < 8; ++ks) {
                if constexpr (V == 5)
                    afrag[ks] = *(const bf16x8*)(A + (size_t)(s * 16 + l16) * 256 + ks * 32 + quad * 8);
                else
                    afrag[ks] = *(const bf16x8*)(A + (size_t)s * 4096 + ks * 512 + lane * 8);
            }
            #pragma unroll
            for (int ks = 0; ks < 8; ++ks)
                asm volatile("" :: "v"(*reinterpret_cast<f32x4*>(&afrag[ks])));
        }
    }
    asm volatile("" :: "v"((int)dummy[threadIdx.x]));
}

extern "C" void kernel_launch(void* const* d_in, const int* in_sizes, int n_in,
                              void* d_out, int out_size, void* d_ws, size_t ws_size,
                              hipStream_t stream)
{
    const float* X   = (const float*)d_in[0];
    const int*   idx = (const int*)d_in[1];
    // d_in[2] = prob_retained (unused, ==1)
    const float* W1  = (const float*)d_in[3];
    const float* b1  = (const float*)d_in[4];
    const float* g1  = (const float*)d_in[5];
    const float* be1 = (const float*)d_in[6];
    const float* W2  = (const float*)d_in[7];
    const float* b2  = (const float*)d_in[8];
    const float* g2  = (const float*)d_in[9];
    const float* be2 = (const float*)d_in[10];
    const float* W3  = (const float*)d_in[11];
    const float* b3  = (const float*)d_in[12];
    const float* g3  = (const float*)d_in[13];
    const float* be3 = (const float*)d_in[14];

    char* ws = (char*)d_ws;
    float* sum1 = (float*)(ws + 0);
    float* sq1  = (float*)(ws + 1024);
    float* sum2 = (float*)(ws + 2048);
    float* sq2  = (float*)(ws + 3072);
    float* sum3 = (float*)(ws + 4096);
    float* sq3  = (float*)(ws + 4608);
    float* s1   = (float*)(ws + 5120);
    float* t1   = (float*)(ws + 6144);
    float* s2   = (float*)(ws + 7168);
    float* t2   = (float*)(ws + 8192);
    float* s3   = (float*)(ws + 9216);
    float* t3   = (float*)(ws + 9728);
    float* b2f  = (float*)(ws + 10240);
    float* b3f  = (float*)(ws + 11264);
    __bf16* W2f = (__bf16*)(ws + 13312);            // 256*256*2 = 131072 B
    __bf16* W3f = (__bf16*)(ws + 144384);           // 128*256*2 = 65536 B
    __bf16* Y1  = (__bf16*)(ws + (1 << 20));                   // [N,256] bf16 51.2 MB
    __bf16* Y2  = (__bf16*)(ws + (1 << 20) + 51200000);        // [N,256] bf16 51.2 MB
    __bf16* Y3  = Y1;  // [N,128]; Y1 dead after gemm2 (gemm3 reads only Y2)

    float* out_nu = (float*)d_out;                  // node_update [N,128] fp32
    float* F      = out_nu + (size_t)NROWS * 128;   // f [N,128] fp32

    const float invN = 1.0f / (float)NROWS;
    const dim3 blk(256);
    const int GB = 512;  // 2 blocks/CU resident, block-strided strips

    hipMemsetAsync(d_ws, 0, 5120, stream);  // zero sum/sumsq accumulators

    // layer 1: X[100000,128] @ W1[256,128]^T (fp32 converted inline)
    gemm_stream<128, 4, true><<<GB, blk, 0, stream>>>(
        nullptr, X, nullptr, W1, b1, Y1, sum1, sq1);
    stats_k<<<1, 256, 0, stream>>>(sum1, sq1, g1, be1, s1, t1, 256, invN);
    fold_k<<<256, 64, 0, stream>>>(W2, b2, s1, t1, W2f, b2f, 256);

    // layer 2: Y1[100000,256] @ W2'[256,256]^T -> Y2
    gemm_stream<256, 4, false><<<GB, blk, 0, stream>>>(
        Y1, nullptr, W2f, nullptr, b2f, Y2, sum2, sq2);
    stats_k<<<1, 256, 0, stream>>>(sum2, sq2, g2, be2, s2, t2, 256, invN);
    fold_k<<<128, 64, 0, stream>>>(W3, b3, s2, t2, W3f, b3f, 256);

    // layer 3: Y2[100000,256] @ W3'[128,256]^T -> raw Y3 (pre-BN) into Y1 region
    gemm_stream<256, 2, false><<<GB, blk, 0, stream>>>(
        Y2, nullptr, W3f, nullptr, b3f, Y3, sum3, sq3);
    stats_k<<<1, 128, 0, stream>>>(sum3, sq3, g3, be3, s3, t3, 128, invN);

    // f = Y3*s3 + t3 -> fp32 F (second half of d_out); gather reads bf16 Y3
    bn_apply<<<6250, 256, 0, stream>>>(Y3, s3, t3, F, (long)NROWS * 128 / 8);
    gather_mean_bn<<<25000, 256, 0, stream>>>(Y3, idx, s3, t3, out_nu, NROWS);

    // ---- diagnostic probes (read-only on dead Y2, write nothing) ----
    probe_loads<5><<<1024, 256, 0, stream>>>(Y2);
    probe_loads<6><<<1024, 256, 0, stream>>>(Y2);
}